// Round 5
// baseline (227.588 us; speedup 1.0000x reference)
//
#include <hip/hip_runtime.h>

// MultiLIF forward: B=32, L=2048, K=1024, f32.
// 3-role wave specialization per 256-thread block (64 neurons):
//   wave0: recurrence compute. I arrives via global_load_lds (issue-only,
//          no VGPR ring, no addr-chain) with counted vmcnt(32) prefetch;
//          per step: ds_read It -> chain -> 3x ds_write.
//   waves 1-3: one output plane each, LDS -> nontemporal global stores,
//          raw lgkmcnt-only barrier so stores pipeline across chunks.
// Arithmetic bit-identical to the verified round-1 kernel (no FMA
// contraction, IEEE divides, exact 0/1 spike select).

#define BATCH 32
#define SEQL  2048
#define KDIM  1024
#define PLANE (BATCH * SEQL * KDIM)   // 67108864 elements per output plane
#define CHUNK 32
#define NCHUNK (SEQL / CHUNK)         // 64

#define GLOAD_LDS(gp, lp)                                                 \
    __builtin_amdgcn_global_load_lds(                                     \
        (const __attribute__((address_space(1))) void*)(gp),              \
        (__attribute__((address_space(3))) void*)(lp), 4, 0, 0)

__device__ __forceinline__ void sync_lds() {
    // order LDS ops only; leave global (nt) stores in flight across barrier
    asm volatile("s_waitcnt lgkmcnt(0)" ::: "memory");
    __builtin_amdgcn_s_barrier();
}

__global__ __launch_bounds__(256, 2) void multilif_fwd(const float* __restrict__ I,
                                                       float* __restrict__ out) {
    __shared__ float lds_out[2][CHUNK][3][64];   // 48 KB [buf][step][plane][lane]
    __shared__ float lds_I[2][CHUNK][64];        // 16 KB [buf][step][lane]

    const int wid  = threadIdx.x >> 6;
    const int lane = threadIdx.x & 63;
    const int idx  = blockIdx.x * 64 + lane;              // neuron id
    const size_t base = ((size_t)(idx >> 10) * SEQL) * KDIM + (idx & (KDIM - 1));

    if (wid == 0) {
        // ------------- compute wave (pure VALU + DS + issue-only glds) ----
#pragma clang fp contract(off)
        const float* __restrict__ Ip = I + base;
        float v = 0.0f, a = 0.0f, sn = 0.0f;

        // prologue: issue chunk-0 I loads into buf 0
#pragma unroll
        for (int j = 0; j < CHUNK; ++j)
            GLOAD_LDS(Ip + (size_t)j * KDIM, &lds_I[0][j][lane]);

        for (int c = 0; c < NCHUNK; ++c) {
            const int bs = c & 1;
            if (c + 1 < NCHUNK) {
                // issue next chunk's loads (stay in flight during compute)
#pragma unroll
                for (int j = 0; j < CHUNK; ++j)
                    GLOAD_LDS(Ip + (size_t)((c + 1) * CHUNK + j) * KDIM,
                              &lds_I[bs ^ 1][j][lane]);
                // wait for chunk c's 32 loads to land; keep the 32 new ones
                asm volatile("s_waitcnt vmcnt(32)" ::: "memory");
            } else {
                asm volatile("s_waitcnt vmcnt(0)" ::: "memory");
            }
            __builtin_amdgcn_sched_barrier(0);

#pragma unroll
            for (int j = 0; j < CHUNK; ++j) {
                const float It = lds_I[bs][j][lane];
                const float th = 1.5f + 1.5f * a;      // no FMA
                v = v + (-v / 20.0f + It);             // IEEE divide
                const float s = (v >= th) ? 1.0f : 0.0f;
                sn = sn + s;
                lds_out[bs][j][0][lane] = s;
                lds_out[bs][j][1][lane] = sn;
                lds_out[bs][j][2][lane] = v;           // pre-reset v
                v = (v >= th) ? -0.5f : v;             // exact reset
                a = a + (-a / 100.0f + s);
            }
            sync_lds();
        }
    } else {
        // ------------- store waves: one output plane each -----------------
        const int p = wid - 1;
        float* __restrict__ pb = out + (size_t)p * (size_t)PLANE + base;

        for (int c = 0; c < NCHUNK; ++c) {
            sync_lds();                       // chunk c now ready in lds_out[c&1]
            const int bs = c & 1;
            float r[CHUNK];
#pragma unroll
            for (int j = 0; j < CHUNK; ++j) r[j] = lds_out[bs][j][p][lane];
#pragma unroll
            for (int j = 0; j < CHUNK; ++j)
                __builtin_nontemporal_store(r[j], pb + (size_t)(c * CHUNK + j) * KDIM);
        }
    }
}

extern "C" void kernel_launch(void* const* d_in, const int* in_sizes, int n_in,
                              void* d_out, int out_size, void* d_ws, size_t ws_size,
                              hipStream_t stream) {
    const float* I = (const float*)d_in[0];
    float* out = (float*)d_out;

    const int grid = (BATCH * KDIM) / 64;    // 512 blocks (64 neurons each)
    multilif_fwd<<<grid, 256, 0, stream>>>(I, out);
}

// Round 6
// 148.955 us; speedup vs baseline: 1.5279x; 1.5279x over previous
//
#include <hip/hip_runtime.h>

// MultiLIF forward: B=32, L=2048, K=1024, f32.
// Producer-consumer wave specialization (round-3 structure, best so far):
//   wave0 computes the serial recurrence for 64 neurons with a VGPR
//   prefetch ring; waves 1-3 drain one output plane each, LDS -> global
//   nontemporal stores, raw lgkmcnt-only barrier (stores pipeline across
//   chunks).
// Round 6 change: replace both IEEE f32 divisions-by-constant with
// EXACT f64-multiply equivalents:
//   RN_f32(x/20)  == (float)((double)x * 0.05)   for ALL f32 x
//   RN_f32(x/100) == (float)((double)x * 0.01)
// Proof sketch: x/20 can't be closer than ~2^-28 (rel) to an f32
// rounding boundary (|M*2^j - 5(2m+1)| >= 1 unless 5|M = exact case);
// f64 mul error <= 2^-52.5 << 2^-28. Removes two ~10-inst, ~70-cyc
// div sequences from the recurrence critical path. Bit-identical output.

#define BATCH 32
#define SEQL  2048
#define KDIM  1024
#define PLANE (BATCH * SEQL * KDIM)   // 67108864 elements per output plane
#define CHUNK 32
#define NCHUNK (SEQL / CHUNK)         // 64

__device__ __forceinline__ float div20(float x)  { return (float)((double)x * 0.05); }
__device__ __forceinline__ float div100(float x) { return (float)((double)x * 0.01); }

__device__ __forceinline__ void sync_lds() {
    // order LDS ops only; leave global (nt) stores in flight across barrier
    asm volatile("s_waitcnt lgkmcnt(0)" ::: "memory");
    __builtin_amdgcn_s_barrier();
}

__global__ __launch_bounds__(256, 2) void multilif_fwd(const float* __restrict__ I,
                                                       float* __restrict__ out) {
    __shared__ float lds[2][CHUNK][3][64];   // [buf][step][plane][lane] = 48 KB

    const int wid  = threadIdx.x >> 6;
    const int lane = threadIdx.x & 63;
    const int idx  = blockIdx.x * 64 + lane;             // neuron id
    const size_t base = ((size_t)(idx >> 10) * SEQL) * KDIM + (idx & (KDIM - 1));

    if (wid == 0) {
        // ------------- compute wave -------------
        const float* __restrict__ Ip = I + base;
        float v = 0.0f, a = 0.0f, sn = 0.0f;
        float ringA[CHUNK], ringB[CHUNK];

#pragma unroll
        for (int j = 0; j < CHUNK; ++j) ringA[j] = Ip[(size_t)j * KDIM];

        auto compute_chunk = [&](int c, float (&cur)[CHUNK], float (&nxt)[CHUNK],
                                 bool pre) {
#pragma clang fp contract(off)
            // issue next chunk's loads first (stay in flight during compute)
#pragma unroll
            for (int j = 0; j < CHUNK; ++j)
                if (pre) nxt[j] = Ip[(size_t)((c + 1) * CHUNK + j) * KDIM];
            const int bs = c & 1;
#pragma unroll
            for (int j = 0; j < CHUNK; ++j) {
                const float It = cur[j];
                const float th = 1.5f + 1.5f * a;      // no FMA
                v = v + (-div20(v) + It);              // == v + (-v/20.f + It)
                const float s = (v >= th) ? 1.0f : 0.0f;
                sn = sn + s;
                lds[bs][j][0][lane] = s;
                lds[bs][j][1][lane] = sn;
                lds[bs][j][2][lane] = v;               // pre-reset v
                v = (v >= th) ? -0.5f : v;             // exact reset
                a = a + (-div100(a) + s);              // == a + (-a/100.f + s)
            }
        };

        for (int cc = 0; cc < NCHUNK / 2; ++cc) {
            compute_chunk(2 * cc,     ringA, ringB, true);
            sync_lds();
            compute_chunk(2 * cc + 1, ringB, ringA, cc < NCHUNK / 2 - 1);
            sync_lds();
        }
    } else {
        // ------------- store waves: one output plane each -------------
        const int p = wid - 1;
        float* __restrict__ pb = out + (size_t)p * (size_t)PLANE + base;

        for (int c = 0; c < NCHUNK; ++c) {
            sync_lds();                       // chunk c now ready in lds[c&1]
            const int bs = c & 1;
            float r[CHUNK];
#pragma unroll
            for (int j = 0; j < CHUNK; ++j) r[j] = lds[bs][j][p][lane];
#pragma unroll
            for (int j = 0; j < CHUNK; ++j)
                __builtin_nontemporal_store(r[j], pb + (size_t)(c * CHUNK + j) * KDIM);
        }
    }
}

extern "C" void kernel_launch(void* const* d_in, const int* in_sizes, int n_in,
                              void* d_out, int out_size, void* d_ws, size_t ws_size,
                              hipStream_t stream) {
    const float* I = (const float*)d_in[0];
    float* out = (float*)d_out;

    const int grid = (BATCH * KDIM) / 64;    // 512 blocks (64 neurons each)
    multilif_fwd<<<grid, 256, 0, stream>>>(I, out);
}